// Round 6
// baseline (111.251 us; speedup 1.0000x reference)
//
#include <hip/hip_runtime.h>
#include <hip/hip_bf16.h>
#include <stdint.h>

// Problem constants (from reference setup_inputs)
#define L_DIM 2048
#define B_DIM 32
#define E_DIM 512
#define HID_DIM 512
#define M_DIM (L_DIM * B_DIM)   // 65536 rows, row m = l*32 + b

typedef float f32x4 __attribute__((ext_vector_type(4)));
typedef short bf16x8 __attribute__((ext_vector_type(8)));

// ws layout (bytes); requires ws_size >= 3211264 (~3.1 MB) — unchanged (known OK)
#define OFF_BASE  0         // 32*512 f32          = 65536
#define OFF_WT    65536     // 512*512 bf16        = 524288  -> 589824
#define OFF_LOGIT 589824    // 65536 f32           = 262144  -> 851968
#define OFF_P     851968    // 65536 f32           = 262144  -> 1114112
#define OFF_PART  1114112   // 32*32*512 f32       = 2097152 -> 3211264

__device__ __forceinline__ unsigned short f2bf(float f) {
  unsigned int u = __float_as_uint(f);
  u = (u + 0x7FFFu + ((u >> 16) & 1u)) >> 16;   // RNE
  return (unsigned short)u;
}

__device__ __forceinline__ float tanh_fast(float x) {
  float xc = fminf(fmaxf(x, -15.f), 15.f);
  float e = __expf(2.f * xc);
  return (e - 1.f) * __builtin_amdgcn_rcpf(e + 1.f);
}

__device__ __forceinline__ uint4 pack8(const float4& a, const float4& b) {
  uint4 r;
  r.x = (unsigned)f2bf(a.x) | ((unsigned)f2bf(a.y) << 16);
  r.y = (unsigned)f2bf(a.z) | ((unsigned)f2bf(a.w) << 16);
  r.z = (unsigned)f2bf(b.x) | ((unsigned)f2bf(b.y) << 16);
  r.w = (unsigned)f2bf(b.z) | ((unsigned)f2bf(b.w) << 16);
  return r;
}

// ---------------- kernel 1: base[b][h] = hidden[b]@W1_h + b1 ----------------
__global__ __launch_bounds__(256) void k_base(const float* __restrict__ hidden,
                                              const float* __restrict__ W1,
                                              const float* __restrict__ b1,
                                              float* __restrict__ base) {
  const int b = blockIdx.x;
  const int tid = threadIdx.x;
  __shared__ float hs[HID_DIM];
  {
    float2 v = *(const float2*)(hidden + (size_t)b * 512 + tid * 2);
    hs[tid * 2] = v.x; hs[tid * 2 + 1] = v.y;
  }
  __syncthreads();
  const int h = tid * 2;
  float2 b1v = *(const float2*)(b1 + h);
  float ax = b1v.x, ay = b1v.y;
#pragma unroll 8
  for (int e = 0; e < 512; ++e) {
    float2 w = *(const float2*)(W1 + (size_t)e * 512 + h);
    float hv = hs[e];
    ax = fmaf(hv, w.x, ax);
    ay = fmaf(hv, w.y, ay);
  }
  float2 r; r.x = ax; r.y = ay;
  *(float2*)(base + (size_t)b * 512 + h) = r;
}

// ------- kernel 2: pre-permute W1_e into MFMA-fragment order ------
// Wt unit index (16B units, 2048 per kc): u = (n>>7)*512 + ((n>>4)&7)*64 + lg*16 + (n&15)
// content: 8 bf16 of W1_e[k = kc*32 + lg*8 + j][n]
__global__ __launch_bounds__(256) void k_prep_wt(const float* __restrict__ W1,
                                                 unsigned short* __restrict__ Wt) {
  const int kc = blockIdx.x;   // 16 blocks
  const int tid = threadIdx.x;
  __shared__ unsigned short sh[32][516];   // +4 pad to spread strided col reads
#pragma unroll
  for (int i = 0; i < 16; ++i) {
    int f4 = i * 256 + tid;                 // 4096 float4 total
    int r = f4 >> 7;                        // 0..31
    int c = (f4 & 127) * 4;                 // 0..508
    float4 v = *(const float4*)(W1 + (size_t)(512 + kc * 32 + r) * 512 + c);
    sh[r][c + 0] = f2bf(v.x); sh[r][c + 1] = f2bf(v.y);
    sh[r][c + 2] = f2bf(v.z); sh[r][c + 3] = f2bf(v.w);
  }
  __syncthreads();
#pragma unroll
  for (int i = 0; i < 8; ++i) {
    int u = i * 256 + tid;                  // 0..2047
    int n = ((u >> 9) << 7) + (((u >> 6) & 7) << 4) + (u & 15);
    int k0 = ((u >> 4) & 3) << 3;
    alignas(16) unsigned short tmp[8];
#pragma unroll
    for (int j = 0; j < 8; ++j) tmp[j] = sh[k0 + j][n];
    *(uint4*)(Wt + ((size_t)kc * 2048 + u) * 8) = *(const uint4*)tmp;
  }
}

// ------- kernel 3: fused GEMM + tanh + W2 reduce -> logit[m] ---------------
// BM=64, full N=512, 8 waves each owning a 64x64 N-slice.
// Phase 1: stage ENTIRE 64x512 x-tile to LDS (bf16, fragment order) — 64 KB
// (4096 16B-units; unit = kc*256 + mi*64 + ks*16 + r15). ONE barrier.
// Phase 2: 16 K-steps of {B frags direct from L2-resident Wt, lane-linear
// ds_read, MFMA} with NO barriers, NO LDS writes. 16 waves/CU (2 blocks)
// hide latency via TLP since nothing synchronizes.
__global__ __launch_bounds__(512, 4) void k_logits(
    const float* __restrict__ x, const unsigned short* __restrict__ Wt,
    const float* __restrict__ base, const float* __restrict__ W2,
    float* __restrict__ logit) {
  __shared__ unsigned short xs[32768];      // 4096 units x 8 bf16 = 64 KB
  const int tid = threadIdx.x;
  const int m0 = blockIdx.x * 64;
  const int w = tid >> 6, lane = tid & 63;  // w = N-slice 0..7
  const int lg = lane >> 4, l15 = lane & 15;

  // ---- phase 1: stage whole x tile, fragment order ----
  // thread: row r = tid>>3, j = tid&7; iter i: k-seg s = i*8+j (8 floats)
  {
    const int r = tid >> 3, j = tid & 7;
    const float* xrow = x + (size_t)(m0 + r) * 512;
    const int ubase = ((r >> 4) << 6) + (r & 15);   // mi*64 + r15
#pragma unroll
    for (int i = 0; i < 8; ++i) {
      int s = i * 8 + j;                    // 0..63
      float4 a0 = *(const float4*)(xrow + s * 8);
      float4 a1 = *(const float4*)(xrow + s * 8 + 4);
      int u = ((s >> 2) << 8) + ((s & 3) << 4) + ubase;  // kc*256 + ks*16 + ...
      *(uint4*)(&xs[u * 8]) = pack8(a0, a1);
    }
  }
  __syncthreads();

  // B fragment base units (per ni): +lane gives the 16B unit within kc-block
  int ub[4];
#pragma unroll
  for (int ni = 0; ni < 4; ++ni) {
    int nb = w * 64 + ni * 16;
    ub[ni] = ((nb >> 7) << 9) + (((nb >> 4) & 7) << 6);
  }

  f32x4 acc[4][4];
#pragma unroll
  for (int mi = 0; mi < 4; ++mi)
#pragma unroll
    for (int ni = 0; ni < 4; ++ni) acc[mi][ni] = (f32x4){0.f, 0.f, 0.f, 0.f};

  // ---- phase 2: barrier-free K loop ----
#pragma unroll 2
  for (int kc = 0; kc < 16; ++kc) {
    uint4 bw[4];
    const uint4* bsrc = (const uint4*)Wt + (size_t)kc * 2048;
#pragma unroll
    for (int ni = 0; ni < 4; ++ni) bw[ni] = bsrc[ub[ni] + lane];
    bf16x8 af[4];
#pragma unroll
    for (int mi = 0; mi < 4; ++mi)
      af[mi] = *(const bf16x8*)(&xs[(kc * 256 + mi * 64 + lane) * 8]);
#pragma unroll
    for (int mi = 0; mi < 4; ++mi)
#pragma unroll
      for (int ni = 0; ni < 4; ++ni)
        acc[mi][ni] = __builtin_amdgcn_mfma_f32_16x16x32_bf16(
            af[mi], *(const bf16x8*)(&bw[ni]), acc[mi][ni], 0, 0, 0);
  }

  // ---- epilogue: pre += base; tanh; dot with W2 slice; reduce ----
  float w2v[4];
#pragma unroll
  for (int ni = 0; ni < 4; ++ni) w2v[ni] = W2[w * 64 + ni * 16 + l15];
  float lsum[4][4];
#pragma unroll
  for (int mi = 0; mi < 4; ++mi) {
#pragma unroll
    for (int rg = 0; rg < 4; ++rg) {
      int m = m0 + mi * 16 + lg * 4 + rg;
      int bb = m & 31;
      const float* brow = base + (size_t)bb * 512 + w * 64;
      float s = 0.f;
#pragma unroll
      for (int ni = 0; ni < 4; ++ni) {
        float pre = acc[mi][ni][rg] + brow[ni * 16 + l15];
        s = fmaf(tanh_fast(pre), w2v[ni], s);
      }
      lsum[mi][rg] = s;
    }
  }
  // reduce 16-col partials within lane groups, then across the 8 waves
  __syncthreads();                          // xs reads done; safe to alias
  float (*lred)[64] = (float (*)[64])xs;    // [w][row64], 2 KB scratch
#pragma unroll
  for (int mi = 0; mi < 4; ++mi)
#pragma unroll
    for (int rg = 0; rg < 4; ++rg) {
      float v = lsum[mi][rg];
      v += __shfl_xor(v, 1); v += __shfl_xor(v, 2);
      v += __shfl_xor(v, 4); v += __shfl_xor(v, 8);
      if (l15 == 0) lred[w][mi * 16 + lg * 4 + rg] = v;
    }
  __syncthreads();
  if (tid < 64) {
    float v = 0.f;
#pragma unroll
    for (int wq = 0; wq < 8; ++wq) v += lred[wq][tid];
    logit[m0 + tid] = v;
  }
}

// ---------------- kernel 4: masked softmax over L per b ----------------
__global__ __launch_bounds__(256) void k_softmax(const float* __restrict__ logit,
                                                 const int* __restrict__ mask,
                                                 float* __restrict__ p) {
  const int b = blockIdx.x, tid = threadIdx.x;
  float lv[8]; float mx = -3.0e38f;
#pragma unroll
  for (int i = 0; i < 8; ++i) {
    int idx = (tid + i * 256) * 32 + b;
    float v = (mask[idx] != 0) ? logit[idx] : -1.0e10f;
    lv[i] = v; mx = fmaxf(mx, v);
  }
  __shared__ float red[8];
  for (int d = 1; d < 64; d <<= 1) mx = fmaxf(mx, __shfl_xor(mx, d));
  if ((tid & 63) == 0) red[tid >> 6] = mx;
  __syncthreads();
  mx = fmaxf(fmaxf(red[0], red[1]), fmaxf(red[2], red[3]));
  float s = 0.f;
#pragma unroll
  for (int i = 0; i < 8; ++i) { lv[i] = __expf(lv[i] - mx); s += lv[i]; }
  for (int d = 1; d < 64; d <<= 1) s += __shfl_xor(s, d);
  __syncthreads();
  if ((tid & 63) == 0) red[4 + (tid >> 6)] = s;
  __syncthreads();
  s = (red[4] + red[5]) + (red[6] + red[7]);
  float inv = 1.f / s;
#pragma unroll
  for (int i = 0; i < 8; ++i) {
    int idx = (tid + i * 256) * 32 + b;
    p[idx] = lv[i] * inv;
  }
}

// ------- kernel 5: partial ctx: part[b][ch][e] = sum_{l in ch} p*x ---------
__global__ __launch_bounds__(128) void k_ctx(const float* __restrict__ x,
                                             const float* __restrict__ p,
                                             float* __restrict__ part) {
  const int blk = blockIdx.x;            // 1024 = 32 b * 32 chunks
  const int b = blk >> 5, ch = blk & 31;
  const int tid = threadIdx.x;           // 128 threads, float4 each
  __shared__ float ps[64];
  const int l0 = ch * 64;
  if (tid < 64) ps[tid] = p[(l0 + tid) * 32 + b];
  __syncthreads();
  const float* xb = x + ((size_t)l0 * 32 + b) * 512 + tid * 4;
  float ax = 0.f, ay = 0.f, az = 0.f, aw = 0.f;
#pragma unroll 4
  for (int i = 0; i < 64; ++i) {
    float4 v = *(const float4*)(xb + (size_t)i * 32 * 512);
    float pv = ps[i];
    ax = fmaf(pv, v.x, ax); ay = fmaf(pv, v.y, ay);
    az = fmaf(pv, v.z, az); aw = fmaf(pv, v.w, aw);
  }
  float4 r; r.x = ax; r.y = ay; r.z = az; r.w = aw;
  *(float4*)(part + (size_t)blk * 512 + tid * 4) = r;
}

// ------- kernel 6: reduce partials -> ctx, concat action_feature -----------
__global__ __launch_bounds__(256) void k_final(const float* __restrict__ part,
                                               const float* __restrict__ af,
                                               float* __restrict__ out) {
  const int b = blockIdx.x, tid = threadIdx.x;
  float ax = 0.f, ay = 0.f;
#pragma unroll
  for (int ch = 0; ch < 32; ++ch) {
    float2 v = *(const float2*)(part + ((size_t)(b * 32 + ch) * 512) + tid * 2);
    ax += v.x; ay += v.y;
  }
  float2 r; r.x = ax; r.y = ay;
  *(float2*)(out + (size_t)b * 1024 + tid * 2) = r;
  float2 a = *(const float2*)(af + (size_t)b * 512 + tid * 2);
  *(float2*)(out + (size_t)b * 1024 + 512 + tid * 2) = a;
}

extern "C" void kernel_launch(void* const* d_in, const int* in_sizes, int n_in,
                              void* d_out, int out_size, void* d_ws, size_t ws_size,
                              hipStream_t stream) {
  const float* x      = (const float*)d_in[0];
  const int*   mask   = (const int*)d_in[1];
  const float* af     = (const float*)d_in[2];
  const float* hidden = (const float*)d_in[3];
  // d_in[4] = state (unused by reference output)
  const float* W1     = (const float*)d_in[5];
  const float* b1     = (const float*)d_in[6];
  const float* W2     = (const float*)d_in[7];
  // d_in[8] = b2 (softmax-invariant, skipped)
  float* out = (float*)d_out;
  char* ws = (char*)d_ws;
  float*          base  = (float*)(ws + OFF_BASE);
  unsigned short* Wt    = (unsigned short*)(ws + OFF_WT);
  float*          logit = (float*)(ws + OFF_LOGIT);
  float*          p     = (float*)(ws + OFF_P);
  float*          part  = (float*)(ws + OFF_PART);

  k_base   <<<32,   256, 0, stream>>>(hidden, W1, b1, base);
  k_prep_wt<<<16,   256, 0, stream>>>(W1, Wt);
  k_logits <<<1024, 512, 0, stream>>>(x, Wt, base, W2, logit);
  k_softmax<<<32,   256, 0, stream>>>(logit, mask, p);
  k_ctx    <<<1024, 128, 0, stream>>>(x, p, part);
  k_final  <<<32,   256, 0, stream>>>(part, af, out);
}